// Round 11
// baseline (389.274 us; speedup 1.0000x reference)
//
#include <hip/hip_runtime.h>
#include <hip/hip_bf16.h>

typedef unsigned short ushort_t;
typedef __attribute__((ext_vector_type(8))) short short8;
typedef __attribute__((ext_vector_type(4))) short short4v;
typedef __attribute__((ext_vector_type(4))) float f32x4;

// Problem constants
constexpr int Hh = 256, Ww = 256, HW = Hh * Ww;
constexpr int Bb = 2, Cc = 64, Pp = 3, NOo = 16, FEXc = 48, Nn = 32768;
constexpr int TW = 32, TH = 8;       // tile per block
constexpr int HALOP = (TH + 2) * 34; // 340 halo pixels (single-conv kernel)
constexpr int AROWS = 352;           // staged rows for single-conv kernel
constexpr int PROWS = 432;           // pair kernel in-tile rows: 36 x 12
constexpr int PADH = 72;             // gather-MLP LDS point stride (bf16)

__device__ inline ushort_t f2bf(float v) {
    __hip_bfloat16 h = __float2bfloat16(v);
    return *(ushort_t*)&h;
}
__device__ inline float bf2f(ushort_t u) {
    __hip_bfloat16 h = *(__hip_bfloat16*)&u;
    return __bfloat162float(h);
}
// async 16B global->LDS DMA: dest = lds base (wave-uniform) + lane*16
__device__ inline void gload_lds16(const ushort_t* g, ushort_t* l) {
    __builtin_amdgcn_global_load_lds(
        (const __attribute__((address_space(1))) unsigned int*)g,
        (__attribute__((address_space(3))) unsigned int*)l, 16, 0, 0);
}

// -------- mask weight: wm = mask / max(avg3x3(mask), 1e-8); also zero the zpage ------
__global__ __launch_bounds__(256) void k_wm(const float* __restrict__ mask,
                                            float* __restrict__ wm,
                                            float* __restrict__ zpage) {
    int pos = blockIdx.x * 256 + threadIdx.x;
    if (blockIdx.x == 0 && threadIdx.x < 64) zpage[threadIdx.x] = 0.f;  // 256B zeros
    int h = pos >> 8, w = pos & 255;
    float s = 0.f;
    #pragma unroll
    for (int dy = -1; dy <= 1; ++dy)
        #pragma unroll
        for (int dx = -1; dx <= 1; ++dx) {
            int hh = h + dy, ww = w + dx;
            if (hh >= 0 && hh < Hh && ww >= 0 && ww < Ww) s += mask[hh * Ww + ww];
        }
    float avg = s * (1.f / 9.f);
    wm[pos] = mask[pos] / fmaxf(avg, 1e-8f);
}

// ---------------- zero a float4 buffer ----------------
__global__ __launch_bounds__(256) void k_zero(float4* __restrict__ p) {
    p[blockIdx.x * 256 + threadIdx.x] = make_float4(0.f, 0.f, 0.f, 0.f);
}

// ---------------- weight transforms: fp32 [oc][cin][3][3] -> bf16 [tap][oc][c64] ----
__global__ __launch_bounds__(256) void k_wx_res(const float* __restrict__ src,
                                                ushort_t* __restrict__ dst) {
    int idx = blockIdx.x * 256 + threadIdx.x;          // < 12*9*64*64 = 442368
    int j = idx / 36864; int rem = idx - j * 36864;
    int t = rem >> 12; int o = (rem >> 6) & 63; int c = rem & 63;
    dst[idx] = f2bf(src[j * 36864 + o * 576 + c * 9 + t]);
}
__global__ __launch_bounds__(256) void k_wx_out(const float* __restrict__ src,
                                                ushort_t* __restrict__ dst) {
    int idx = blockIdx.x * 256 + threadIdx.x;          // < 3*9*16*64 = 27648
    int i = idx / 9216; int rem = idx - i * 9216;
    int t = rem >> 10; int o = (rem >> 6) & 15; int c = rem & 63;
    dst[idx] = f2bf(src[i * 9216 + o * 576 + c * 9 + t]);
}
__global__ __launch_bounds__(256) void k_wx_trunk(const float* __restrict__ src,
                                                  ushort_t* __restrict__ dst) {
    int idx = blockIdx.x * 256 + threadIdx.x;          // < 4*9*48*64 = 110592
    int j = idx / 27648; int rem = idx - j * 27648;
    int t = rem / 3072; int rem2 = rem - t * 3072;
    int o = rem2 >> 6; int c = rem2 & 63;
    float v = (c < 48) ? src[j * (48 * 48 * 9) + o * 432 + c * 9 + t] : 0.f;
    dst[idx] = f2bf(v);
}
// MLP weights -> A-frag layout [out][k64] bf16, biases folded
__global__ __launch_bounds__(256) void k_wx_mlp(
    const float* __restrict__ w1, const float* __restrict__ b1,
    const float* __restrict__ w2, const float* __restrict__ b2,
    const float* __restrict__ w3, const float* __restrict__ b3,
    ushort_t* __restrict__ dst) {
    int idx = blockIdx.x * 256 + threadIdx.x;          // < 7168
    float v = 0.f;
    if (idx < 3072) {                                  // wA1 [48][64]
        int o = idx >> 6, c = idx & 63;
        v = (c < 49) ? w1[o * 49 + c] : (c == 49 ? b1[o] : 0.f);
    } else if (idx < 6144) {                           // wA2 [48][64]
        int o = (idx - 3072) >> 6, c = idx & 63;
        v = (c < 48) ? w2[o * 48 + c] : (c == 48 ? b2[o] : 0.f);
    } else {                                           // wA3 [16][64]
        int o = (idx - 6144) >> 6, c = idx & 63;
        if (o < 3) v = (c < 48) ? w3[o * 48 + c] : (c == 49 ? b3[o] : 0.f);
    }
    dst[idx] = f2bf(v);
}

// ------- xs: NCHW fp32 -> masked NHWC bf16, all pyramids (z = i*B + b) --------------
__global__ __launch_bounds__(256) void k_xm(const float* __restrict__ xs,
                                            const float* __restrict__ mask,
                                            ushort_t* __restrict__ X) {
    __shared__ float l[64 * 65];
    const int p0 = blockIdx.x * 64;
    const size_t zoff = (size_t)blockIdx.y * 64 * HW;
    const int tid = threadIdx.x;
    const int px = tid & 63;
    const float mv = mask[p0 + px];
    #pragma unroll
    for (int k = 0; k < 16; ++k) {
        int c = (tid >> 6) + 4 * k;
        l[c * 65 + px] = xs[zoff + (size_t)c * HW + p0 + px] * mv;
    }
    __syncthreads();
    #pragma unroll
    for (int k = 0; k < 2; ++k) {
        int idx = tid + k * 256;
        int p = idx >> 3, c8 = idx & 7;
        short8 v;
        #pragma unroll
        for (int i = 0; i < 8; ++i) v[i] = (short)f2bf(l[(c8 * 8 + i) * 65 + p]);
        *(short8*)&X[zoff + (size_t)(p0 + p) * 64 + c8 * 8] = v;
    }
}

// ---------------- FUSED resblock: out = in + conv2(relu(conv1(in)*wm))*wm -----------
// In-tile 36x12 (halo 2) staged once (8-slot XOR swizzle, zero-page OOB). conv1
// computed on mid 34x10 (waves own rows {0-2,3-5,6-7,8-9} x 3 col-frags; col-frag 2
// clamped to tile, garbage lanes never stored). Residual base pre-read to regs, then
// mid (relu*wm, bf16) stored into the SAME LDS region (alias) with the mpx swizzle.
// conv2 = standard 16px-frag loop over mid. Weights per 32ch phase from L2 (4 stages).
// NOTE: no extra global base is added — gather computes F+G, so trunk G must be g2.
template <int OC, int MODE>
__global__ __launch_bounds__(256) void k_pair(
    const ushort_t* __restrict__ in,
    const ushort_t* __restrict__ wgt, int wstride,
    const float* __restrict__ wm,
    const ushort_t* __restrict__ zp,
    const ushort_t* __restrict__ fb,
    ushort_t* __restrict__ out) {
    constexpr int NM = OC / 16;
    constexpr int WROWS = 9 * OC;
    constexpr int WDMA = WROWS / 16;
    constexpr int C2OFF = 9 * OC * 64;
    extern __shared__ __align__(1024) ushort_t smem[];
    ushort_t* alds = smem;                  // PROWS x 64 (also aliased as mid 340 x 64)
    ushort_t* mlds = smem;                  // alias: mid stored after base pre-read
    ushort_t* wlds = smem + PROWS * 64;     // WROWS x 32
    const int tid = threadIdx.x, wv = tid >> 6, ln = tid & 63;
    const int lo = ln & 15, slr = ln >> 4;
    const int w0 = blockIdx.x * TW, h0 = blockIdx.y * TH;
    const int zz = blockIdx.z;
    const ushort_t* inb = in + (size_t)zz * HW * 64;
    ushort_t* outb = out + (size_t)zz * HW * 64;
    const ushort_t* wg1 = wgt + (size_t)(zz >> 1) * wstride;

    auto wstage = [&](const ushort_t* ws, int ck) {
        #pragma unroll
        for (int k = 0; k < (WDMA + 3) / 4; ++k) {
            int s = wv + 4 * k;
            if (s < WDMA) {
                int r = s * 16 + (ln >> 2);
                int d = ln & 3;
                int j = d ^ ((r ^ (r >> 2)) & 3);
                gload_lds16(ws + (size_t)r * 64 + ck * 32 + j * 8, &wlds[s * 512]);
            }
        }
    };

    // ---- stage 36x12 in-tile: 54 DMA ----
    #pragma unroll
    for (int k = 0; k < 14; ++k) {
        int s = 4 * k + wv;
        if (s < 54) {
            int pp = s * 8 + (ln >> 3);
            int r = (pp * 228) >> 13;          // pp/36 for pp<432
            int col = pp - r * 36;
            int gh = h0 + r - 2, gw = w0 + col - 2;
            bool ok = (gh >= 0) & (gh < Hh) & (gw >= 0) & (gw < Ww);
            int che = ((ln & 7) ^ (pp & 7)) << 3;
            const ushort_t* src = ok ? inb + (size_t)(gh * Ww + gw) * 64 + che : zp + che;
            gload_lds16(src, &alds[s * 512]);
        }
    }
    wstage(wg1, 0);
    asm volatile("s_waitcnt vmcnt(0)" ::: "memory");
    __syncthreads();

    // ---- conv1 on mid rows rb..rb+nr-1 ----
    const int rb = (wv < 3) ? wv * 3 : 8;
    const int nr = (wv < 2) ? 3 : 2;
    f32x4 a1[NM][3][3];
    #pragma unroll
    for (int mf = 0; mf < NM; ++mf)
        #pragma unroll
        for (int j = 0; j < 3; ++j)
            #pragma unroll
            for (int cf = 0; cf < 3; ++cf) a1[mf][j][cf] = (f32x4){0.f, 0.f, 0.f, 0.f};

    #pragma unroll
    for (int h = 0; h < 2; ++h) {
        if (h) {
            __syncthreads();
            wstage(wg1, 1);
            asm volatile("s_waitcnt vmcnt(0)" ::: "memory");
            __syncthreads();
        }
        #pragma unroll
        for (int dy = 0; dy < 3; ++dy)
            #pragma unroll
            for (int dx = 0; dx < 3; ++dx) {
                const int t = dy * 3 + dx;
                short8 af[NM];
                #pragma unroll
                for (int mf = 0; mf < NM; ++mf) {
                    int r = t * OC + mf * 16 + lo;
                    af[mf] = *(const short8*)&wlds[r * 32 + ((slr ^ ((r ^ (r >> 2)) & 3)) << 3)];
                }
                #pragma unroll
                for (int j = 0; j < 3; ++j) if (j < nr) {
                    #pragma unroll
                    for (int cf = 0; cf < 3; ++cf) {
                        int cc = cf * 16 + lo + dx;
                        if (cf == 2) cc = min(cc, 35);   // clamp into tile; lanes lo>=2 discarded
                        int pp2 = (rb + j + dy) * 36 + cc;
                        short8 b = *(const short8*)&alds[pp2 * 64 + (((h * 4 + slr) ^ (pp2 & 7)) << 3)];
                        #pragma unroll
                        for (int mf = 0; mf < NM; ++mf)
                            a1[mf][j][cf] = __builtin_amdgcn_mfma_f32_16x16x32_bf16(
                                af[mf], b, a1[mf][j][cf], 0, 0, 0);
                    }
                }
            }
    }

    // ---- pre-read residual base (in-tile center) into regs before aliasing ----
    short4v bres[4][NM];
    #pragma unroll
    for (int nf = 0; nf < 4; ++nf) {
        int ppb = (2 * wv + (nf >> 1) + 2) * 36 + (nf & 1) * 16 + lo + 2;
        #pragma unroll
        for (int mf = 0; mf < NM; ++mf) {
            int o0 = mf * 16 + slr * 4;
            bres[nf][mf] = *(const short4v*)
                &alds[ppb * 64 + (((o0 >> 3) ^ (ppb & 7)) << 3) + (slr & 1) * 4];
        }
    }
    __syncthreads();   // all conv1 reads + base reads done before mid overwrites alds

    // ---- relu * wm(mid px), store mid bf16 into mlds (alias of alds) ----
    #pragma unroll
    for (int j = 0; j < 3; ++j) if (j < nr) {
        int mr = rb + j;
        #pragma unroll
        for (int cf = 0; cf < 3; ++cf) {
            int mc = cf * 16 + lo;
            if (mc < 34) {
                int gh = h0 + mr - 1, gw = w0 + mc - 1;
                bool ok = (gh >= 0) & (gh < Hh) & (gw >= 0) & (gw < Ww);
                float wmv = ok ? wm[gh * Ww + gw] : 0.f;
                int mpx = mr * 34 + mc;
                #pragma unroll
                for (int mf = 0; mf < NM; ++mf) {
                    int o0 = mf * 16 + slr * 4;
                    short4v sv;
                    #pragma unroll
                    for (int q = 0; q < 4; ++q)
                        sv[q] = (short)f2bf(fmaxf(a1[mf][j][cf][q] * wmv, 0.f));
                    *(short4v*)&mlds[mpx * 64 + (((o0 >> 3) ^ (mpx & 7)) << 3) + (slr & 1) * 4] = sv;
                }
                if (OC < 64) {                      // zero mid ch 48..63 (trunk)
                    int o0 = 48 + slr * 4;
                    short4v zv = {0, 0, 0, 0};
                    *(short4v*)&mlds[mpx * 64 + (((o0 >> 3) ^ (mpx & 7)) << 3) + (slr & 1) * 4] = zv;
                }
            }
        }
    }
    __syncthreads();
    wstage(wg1 + C2OFF, 0);
    asm volatile("s_waitcnt vmcnt(0)" ::: "memory");
    __syncthreads();

    // ---- conv2 over mid (34-wide), standard geometry ----
    f32x4 a2[NM][4];
    #pragma unroll
    for (int mf = 0; mf < NM; ++mf)
        #pragma unroll
        for (int nf = 0; nf < 4; ++nf) a2[mf][nf] = (f32x4){0.f, 0.f, 0.f, 0.f};

    #pragma unroll
    for (int h = 0; h < 2; ++h) {
        if (h) {
            __syncthreads();
            wstage(wg1 + C2OFF, 1);
            asm volatile("s_waitcnt vmcnt(0)" ::: "memory");
            __syncthreads();
        }
        #pragma unroll
        for (int dy = 0; dy < 3; ++dy)
            #pragma unroll
            for (int dx = 0; dx < 3; ++dx) {
                const int t = dy * 3 + dx;
                short8 af[NM];
                #pragma unroll
                for (int mf = 0; mf < NM; ++mf) {
                    int r = t * OC + mf * 16 + lo;
                    af[mf] = *(const short8*)&wlds[r * 32 + ((slr ^ ((r ^ (r >> 2)) & 3)) << 3)];
                }
                short8 bfr[4];
                #pragma unroll
                for (int nf = 0; nf < 4; ++nf) {
                    int pp2 = (2 * wv + (nf >> 1) + dy) * 34 + (nf & 1) * 16 + lo + dx;
                    bfr[nf] = *(const short8*)&mlds[pp2 * 64 + (((h * 4 + slr) ^ (pp2 & 7)) << 3)];
                }
                #pragma unroll
                for (int mf = 0; mf < NM; ++mf)
                    #pragma unroll
                    for (int nf = 0; nf < 4; ++nf)
                        a2[mf][nf] = __builtin_amdgcn_mfma_f32_16x16x32_bf16(
                            af[mf], bfr[nf], a2[mf][nf], 0, 0, 0);
            }
    }

    // ---- epilogue: out = base + conv2*wm (+fb if MODE 1) ----
    #pragma unroll
    for (int nf = 0; nf < 4; ++nf) {
        int r = h0 + 2 * wv + (nf >> 1);
        int x = w0 + (nf & 1) * 16 + lo;
        int pos = r * Ww + x;
        float wmv = wm[pos];
        #pragma unroll
        for (int mf = 0; mf < NM; ++mf) {
            int o0 = mf * 16 + slr * 4;
            size_t oi = (size_t)pos * 64 + o0;
            float v[4];
            #pragma unroll
            for (int q = 0; q < 4; ++q)
                v[q] = a2[mf][nf][q] * wmv + bf2f((ushort_t)bres[nf][mf][q]);
            if (MODE == 1) {
                short4v fv = *(const short4v*)&fb[(size_t)zz * HW * 64 + oi];
                #pragma unroll
                for (int q = 0; q < 4; ++q) v[q] += bf2f((ushort_t)fv[q]);
            }
            short4v sv;
            #pragma unroll
            for (int q = 0; q < 4; ++q) sv[q] = (short)f2bf(v[q]);
            *(short4v*)&outb[oi] = sv;
        }
    }
}

// ---------------- single MFMA conv (used for conv5: 64->16 into F) ------------------
template <int OC, int MODE, bool TOF>
__global__ __launch_bounds__(256) void k_mconv(
    const ushort_t* __restrict__ in,
    const ushort_t* __restrict__ wgt, int wstride,
    const float* __restrict__ wm,
    const ushort_t* __restrict__ zp,
    const ushort_t* __restrict__ base,
    ushort_t* __restrict__ out) {
    constexpr int NM = OC / 16;
    constexpr int WROWS = 9 * OC;
    constexpr int WDMA = WROWS / 16;
    extern __shared__ __align__(1024) ushort_t smem[];
    ushort_t* alds = smem;
    ushort_t* wlds = smem + AROWS * 64;
    const int tid = threadIdx.x;
    const int wv = tid >> 6;
    const int ln = tid & 63;
    const int w0 = blockIdx.x * TW, h0 = blockIdx.y * TH;
    const int zz = blockIdx.z;
    const ushort_t* inb = in + (size_t)zz * HW * 64;
    const ushort_t* wB = wgt + (size_t)(zz >> 1) * wstride;
    const ushort_t* baseb = base ? base + (size_t)zz * HW * 64 : nullptr;
    ushort_t* outb = TOF ? out + (size_t)(zz & 1) * HW * 64 : out + (size_t)zz * HW * 64;
    const int ocb = TOF ? (zz >> 1) * 16 : 0;

    const int lo = ln & 15, slr = ln >> 4, g8 = slr * 8;

    f32x4 acc[NM][4];
    #pragma unroll
    for (int mf = 0; mf < NM; ++mf)
        #pragma unroll
        for (int nf = 0; nf < 4; ++nf) acc[mf][nf] = (f32x4){0.f, 0.f, 0.f, 0.f};

    #pragma unroll
    for (int k = 0; k < 11; ++k) {
        int s = wv * 11 + k;
        int pp = s * 8 + (ln >> 3);
        int r = (pp * 241) >> 13;              // pp/34 for pp<352
        int col = pp - r * 34;
        int gh = h0 + r - 1, gw = w0 + col - 1;
        bool ok = (pp < HALOP) & (gh >= 0) & (gh < Hh) & (gw >= 0) & (gw < Ww);
        int che = ((ln & 7) ^ (pp & 7)) << 3;
        const ushort_t* src = ok ? inb + (size_t)(gh * Ww + gw) * 64 + che : zp + che;
        gload_lds16(src, &alds[s * 512]);
    }

    #pragma unroll
    for (int h = 0; h < 2; ++h) {
        if (h) __syncthreads();
        #pragma unroll
        for (int k = 0; k < (WDMA + 3) / 4; ++k) {
            int s = wv + 4 * k;
            if (s < WDMA) {
                int r = s * 16 + (ln >> 2);
                int d = ln & 3;
                int j = d ^ ((r ^ (r >> 2)) & 3);
                gload_lds16(wB + (size_t)r * 64 + h * 32 + j * 8, &wlds[s * 512]);
            }
        }
        asm volatile("s_waitcnt vmcnt(0)" ::: "memory");
        __syncthreads();

        #pragma unroll
        for (int dy = 0; dy < 3; ++dy)
            #pragma unroll
            for (int dx = 0; dx < 3; ++dx) {
                const int t = dy * 3 + dx;
                short8 bfr[4];
                #pragma unroll
                for (int nf = 0; nf < 4; ++nf) {
                    int pp2 = (2 * wv + (nf >> 1) + dy) * 34 + (nf & 1) * 16 + lo + dx;
                    bfr[nf] = *(const short8*)
                        &alds[pp2 * 64 + (((h * 4 + slr) ^ (pp2 & 7)) << 3)];
                }
                short8 afr[NM];
                #pragma unroll
                for (int mf = 0; mf < NM; ++mf) {
                    int r = t * OC + mf * 16 + lo;
                    afr[mf] = *(const short8*)
                        &wlds[r * 32 + ((slr ^ ((r ^ (r >> 2)) & 3)) << 3)];
                }
                #pragma unroll
                for (int mf = 0; mf < NM; ++mf)
                    #pragma unroll
                    for (int nf = 0; nf < 4; ++nf)
                        acc[mf][nf] = __builtin_amdgcn_mfma_f32_16x16x32_bf16(
                            afr[mf], bfr[nf], acc[mf][nf], 0, 0, 0);
            }
    }

    #pragma unroll
    for (int nf = 0; nf < 4; ++nf) {
        int r = h0 + 2 * wv + (nf >> 1);
        int x = w0 + (nf & 1) * 16 + lo;
        int pos = r * Ww + x;
        float wmv = wm[pos];
        #pragma unroll
        for (int mf = 0; mf < NM; ++mf) {
            int o0 = ocb + mf * 16 + slr * 4;
            size_t oi = (size_t)pos * 64 + o0;
            float v[4];
            #pragma unroll
            for (int j = 0; j < 4; ++j) v[j] = acc[mf][nf][j] * wmv;
            if (MODE == 0) {
                #pragma unroll
                for (int j = 0; j < 4; ++j) v[j] = fmaxf(v[j], 0.f);
            } else if (MODE == 1) {
                short4v bv = *(const short4v*)&baseb[oi];
                #pragma unroll
                for (int j = 0; j < 4; ++j) v[j] += bf2f((ushort_t)bv[j]);
            }
            short4v sv;
            #pragma unroll
            for (int j = 0; j < 4; ++j) sv[j] = (short)f2bf(v[j]);
            *(short4v*)&outb[oi] = sv;
        }
    }
}

// ---------------- gather + MLP via MFMA: 64 pts/block, 16 pts/wave --------------------
__global__ __launch_bounds__(256) void k_gather_mlp(
    const ushort_t* __restrict__ F, const ushort_t* __restrict__ G,
    const int* __restrict__ yi, const float* __restrict__ m,
    const ushort_t* __restrict__ wA1, const ushort_t* __restrict__ wA2,
    const ushort_t* __restrict__ wA3, float* __restrict__ pvd) {
    __shared__ __align__(16) ushort_t HA[4 * 16 * PADH];
    __shared__ __align__(16) ushort_t HB[4 * 16 * PADH];
    const int tid = threadIdx.x, wv = tid >> 6, ln = tid & 63;
    ushort_t* ha = HA + wv * 16 * PADH;
    ushort_t* hb = HB + wv * 16 * PADH;
    const int t0 = blockIdx.x * 64 + wv * 16;
    const int b = t0 >> 15;
    const int lo = ln & 15, g8 = (ln >> 4) * 8;

    #pragma unroll
    for (int rnd = 0; rnd < 2; ++rnd) {
        int j = rnd * 64 + ln;
        if (j < 96) {
            int pt = j / 6, sl = j - pt * 6;
            int n = (t0 + pt) & (Nn - 1);
            int pos = yi[n];
            size_t gi = ((size_t)(b * HW) + pos) * 64 + sl * 8;
            short8 fa = *(const short8*)&F[gi];
            short8 ga = *(const short8*)&G[gi];
            short8 sv;
            #pragma unroll
            for (int i = 0; i < 8; ++i)
                sv[i] = (short)f2bf(bf2f((ushort_t)fa[i]) + bf2f((ushort_t)ga[i]));
            *(short8*)&ha[pt * PADH + sl * 8] = sv;
        }
    }
    if (ln < 16) {
        int pt = ln;
        int n = (t0 + pt) & (Nn - 1);
        int pos = yi[n];
        float det = m[0] * (m[4] * m[8] - m[5] * m[7])
                  - m[1] * (m[3] * m[8] - m[5] * m[6])
                  + m[2] * (m[3] * m[7] - m[4] * m[6]);
        int yr = pos >> 8, xc = pos & 255;
        float wc = m[6] * (float)xc + m[7] * (float)yr + m[8];
        float cw = fmaxf(fabsf(wc), 1e-8f);
        float dsda = fabsf(det) / (cw * cw * cw);
        float ld = logf(dsda + 1e-8f);
        const ushort_t one = f2bf(1.0f);
        short8 z = {0, 0, 0, 0, 0, 0, 0, 0};
        short8 sa = z; sa[0] = (short)f2bf(ld); sa[1] = (short)one;
        short8 sb = z; sb[0] = (short)one;
        *(short8*)&ha[pt * PADH + 48] = sa;
        *(short8*)&ha[pt * PADH + 56] = z;
        *(short8*)&hb[pt * PADH + 48] = sb;
        *(short8*)&hb[pt * PADH + 56] = z;
    }
    asm volatile("s_waitcnt lgkmcnt(0)" ::: "memory");

    f32x4 a1[3] = {{0.f,0.f,0.f,0.f},{0.f,0.f,0.f,0.f},{0.f,0.f,0.f,0.f}};
    #pragma unroll
    for (int ks = 0; ks < 2; ++ks) {
        short8 bf = *(const short8*)&ha[lo * PADH + ks * 32 + g8];
        #pragma unroll
        for (int mf = 0; mf < 3; ++mf) {
            short8 af = *(const short8*)&wA1[(mf * 16 + lo) * 64 + ks * 32 + g8];
            a1[mf] = __builtin_amdgcn_mfma_f32_16x16x32_bf16(af, bf, a1[mf], 0, 0, 0);
        }
    }
    #pragma unroll
    for (int mf = 0; mf < 3; ++mf) {
        short4v sv;
        #pragma unroll
        for (int j = 0; j < 4; ++j) sv[j] = (short)f2bf(fmaxf(a1[mf][j], 0.f));
        *(short4v*)&hb[lo * PADH + mf * 16 + (ln >> 4) * 4] = sv;
    }
    asm volatile("s_waitcnt lgkmcnt(0)" ::: "memory");

    f32x4 a2[3] = {{0.f,0.f,0.f,0.f},{0.f,0.f,0.f,0.f},{0.f,0.f,0.f,0.f}};
    #pragma unroll
    for (int ks = 0; ks < 2; ++ks) {
        short8 bf = *(const short8*)&hb[lo * PADH + ks * 32 + g8];
        #pragma unroll
        for (int mf = 0; mf < 3; ++mf) {
            short8 af = *(const short8*)&wA2[(mf * 16 + lo) * 64 + ks * 32 + g8];
            a2[mf] = __builtin_amdgcn_mfma_f32_16x16x32_bf16(af, bf, a2[mf], 0, 0, 0);
        }
    }
    #pragma unroll
    for (int mf = 0; mf < 3; ++mf) {
        short4v sv;
        #pragma unroll
        for (int j = 0; j < 4; ++j) sv[j] = (short)f2bf(fmaxf(a2[mf][j], 0.f));
        *(short4v*)&ha[lo * PADH + mf * 16 + (ln >> 4) * 4] = sv;
    }
    asm volatile("s_waitcnt lgkmcnt(0)" ::: "memory");

    f32x4 a3 = {0.f, 0.f, 0.f, 0.f};
    #pragma unroll
    for (int ks = 0; ks < 2; ++ks) {
        short8 bf = *(const short8*)&ha[lo * PADH + ks * 32 + g8];
        short8 af = *(const short8*)&wA3[lo * 64 + ks * 32 + g8];
        a3 = __builtin_amdgcn_mfma_f32_16x16x32_bf16(af, bf, a3, 0, 0, 0);
    }
    if (ln < 16) {
        int n = (t0 + lo) & (Nn - 1);
        int pos = yi[n];
        #pragma unroll
        for (int j = 0; j < 3; ++j)
            pvd[(size_t)(b * Pp + j) * HW + pos] = a3[j];
    }
}

// ---------------- out[b,c,pos] = sum_p pvd[b,p,pos] * xs[p,b,c,pos] ----------------
__global__ __launch_bounds__(256) void k_blend(const float4* __restrict__ xs,
                                               const float4* __restrict__ pvd,
                                               float4* __restrict__ out) {
    int i = blockIdx.x * 256 + threadIdx.x;   // over B*C*HW/4
    int pos4 = i & (HW / 4 - 1);
    int bc = i >> 14;
    int b = bc >> 6;
    float4 acc = make_float4(0.f, 0.f, 0.f, 0.f);
    #pragma unroll
    for (int p = 0; p < Pp; ++p) {
        float4 pv = pvd[(b * Pp + p) * (HW / 4) + pos4];
        float4 x = xs[p * (Bb * Cc * HW / 4) + i];
        acc.x += pv.x * x.x;
        acc.y += pv.y * x.y;
        acc.z += pv.z * x.z;
        acc.w += pv.w * x.w;
    }
    out[i] = acc;
}

extern "C" void kernel_launch(void* const* d_in, const int* in_sizes, int n_in,
                              void* d_out, int out_size, void* d_ws, size_t ws_size,
                              hipStream_t stream) {
    const float* xs        = (const float*)d_in[0];
    const float* mask      = (const float*)d_in[1];
    const int*   yi        = (const int*)d_in[2];
    const float* m         = (const float*)d_in[3];
    const float* ss_res_w  = (const float*)d_in[4];
    const float* ss_out_w  = (const float*)d_in[5];
    const float* feat_res_w= (const float*)d_in[6];
    const float* w1 = (const float*)d_in[7];
    const float* b1 = (const float*)d_in[8];
    const float* w2 = (const float*)d_in[9];
    const float* b2 = (const float*)d_in[10];
    const float* w3 = (const float*)d_in[11];
    const float* b3 = (const float*)d_in[12];

    // ws: wm f32 | zpage | pvd f32 | wB | wA | X (P,B,HW,64) | U | V | F (B,HW,64) | G
    float* wm    = (float*)d_ws;
    float* zpage = wm + HW;
    float* pvd   = zpage + 64;
    ushort_t* wB = (ushort_t*)(pvd + (size_t)Bb * Pp * HW);
    constexpr size_t RES_T = 12 * 9 * 64 * 64;     // 442368
    constexpr size_t OUT_T = 3 * 9 * 16 * 64;      // 27648
    constexpr size_t TRK_T = 4 * 9 * 48 * 64;      // 110592
    constexpr size_t MLP_T = 7168;
    constexpr size_t ZT = (size_t)Pp * Bb * HW * 64;   // 25165824
    ushort_t* wA = wB + RES_T + OUT_T + TRK_T;
    ushort_t* X = wA + MLP_T;
    ushort_t* U = X + ZT;
    ushort_t* V = U + ZT;
    ushort_t* F = V + ZT;
    ushort_t* G = F + (size_t)Bb * HW * 64;
    const ushort_t* zp = (const ushort_t*)zpage;

    k_wm<<<HW / 256, 256, 0, stream>>>(mask, wm, zpage);
    k_wx_res  <<<RES_T / 256, 256, 0, stream>>>(ss_res_w, wB);
    k_wx_out  <<<OUT_T / 256, 256, 0, stream>>>(ss_out_w, wB + RES_T);
    k_wx_trunk<<<TRK_T / 256, 256, 0, stream>>>(feat_res_w, wB + RES_T + OUT_T);
    k_wx_mlp  <<<MLP_T / 256, 256, 0, stream>>>(w1, b1, w2, b2, w3, b3, wA);

    const dim3 gridP(Ww / TW, Hh / TH, Pp * Bb);   // (8, 32, 6)
    const dim3 gridT(Ww / TW, Hh / TH, Bb);        // (8, 32, 2)
    const int RS = 4 * 9 * 64 * 64;                // per-pyramid res weight stride
    const int OS = 9 * 16 * 64;                    // per-pyramid out weight stride
    constexpr size_t PSH64 = (size_t)(PROWS * 64 + 9 * 64 * 32) * 2;   // 92160
    constexpr size_t PSH48 = (size_t)(PROWS * 64 + 9 * 48 * 32) * 2;   // 82944
    constexpr size_t SH16  = (size_t)AROWS * 128 + 9 * 16 * 64;        // 54272

    k_xm<<<dim3(HW / 64, Pp * Bb), 256, 0, stream>>>(xs, mask, X);
    // pyramid resblocks fused: X -> V -> U, then conv5: U -> F
    k_pair<64, 0><<<gridP, 256, PSH64, stream>>>(X, wB,             RS, wm, zp, nullptr, V);
    k_pair<64, 0><<<gridP, 256, PSH64, stream>>>(V, wB + 2 * 36864, RS, wm, zp, nullptr, U);
    k_mconv<16, 2, true><<<gridP, 256, SH16, stream>>>(U, wB + RES_T, OS, wm, zp, nullptr, F);
    // trunk: g1 = F + c2relu(c1 F) -> U ; G = g1 + c2relu(c1 g1) = g2  (gather adds F)
    const ushort_t* tw = wB + RES_T + OUT_T;
    k_pair<48, 0><<<gridT, 256, PSH48, stream>>>(F, tw,             0, wm, zp, nullptr, U);
    k_pair<48, 0><<<gridT, 256, PSH48, stream>>>(U, tw + 2 * 27648, 0, wm, zp, nullptr, G);

    k_zero<<<(Bb * Pp * HW / 4) / 256, 256, 0, stream>>>((float4*)pvd);
    k_gather_mlp<<<Bb * Nn / 64, 256, 0, stream>>>(F, G, yi, m,
        wA, wA + 3072, wA + 6144, pvd);
    k_blend<<<(Bb * Cc * HW / 4) / 256, 256, 0, stream>>>((const float4*)xs, (const float4*)pvd,
                                                          (float4*)d_out);
}

// Round 12
// 340.134 us; speedup vs baseline: 1.1445x; 1.1445x over previous
//
#include <hip/hip_runtime.h>
#include <hip/hip_bf16.h>

typedef unsigned short ushort_t;
typedef __attribute__((ext_vector_type(8))) short short8;
typedef __attribute__((ext_vector_type(4))) short short4v;
typedef __attribute__((ext_vector_type(4))) float f32x4;

// Problem constants
constexpr int Hh = 256, Ww = 256, HW = Hh * Ww;
constexpr int Bb = 2, Cc = 64, Pp = 3, NOo = 16, FEXc = 48, Nn = 32768;
constexpr int TW = 32, TH = 4;       // conv tile per block
constexpr int HALOP4 = 6 * 34;       // 204 halo pixels
constexpr int ASLOT = 26;            // act DMA slots (8 rows each) -> 208 rows
constexpr int PADH = 72;             // gather-MLP LDS point stride (bf16)

__device__ inline ushort_t f2bf(float v) {
    __hip_bfloat16 h = __float2bfloat16(v);
    return *(ushort_t*)&h;
}
__device__ inline float bf2f(ushort_t u) {
    __hip_bfloat16 h = *(__hip_bfloat16*)&u;
    return __bfloat162float(h);
}
// async 16B global->LDS DMA: dest = lds base (wave-uniform) + lane*16
__device__ inline void gload_lds16(const ushort_t* g, ushort_t* l) {
    __builtin_amdgcn_global_load_lds(
        (const __attribute__((address_space(1))) unsigned int*)g,
        (__attribute__((address_space(3))) unsigned int*)l, 16, 0, 0);
}
template <int N>
__device__ __forceinline__ void wait_vm() {
    if constexpr (N == 0) asm volatile("s_waitcnt vmcnt(0)" ::: "memory");
    else if constexpr (N == 3) asm volatile("s_waitcnt vmcnt(3)" ::: "memory");
    else if constexpr (N == 5) asm volatile("s_waitcnt vmcnt(5)" ::: "memory");
}

// -------- mask weight: wm = mask / max(avg3x3(mask), 1e-8); also zero the zpage ------
__global__ __launch_bounds__(256) void k_wm(const float* __restrict__ mask,
                                            float* __restrict__ wm,
                                            float* __restrict__ zpage) {
    int pos = blockIdx.x * 256 + threadIdx.x;
    if (blockIdx.x == 0 && threadIdx.x < 64) zpage[threadIdx.x] = 0.f;  // 256B zeros
    int h = pos >> 8, w = pos & 255;
    float s = 0.f;
    #pragma unroll
    for (int dy = -1; dy <= 1; ++dy)
        #pragma unroll
        for (int dx = -1; dx <= 1; ++dx) {
            int hh = h + dy, ww = w + dx;
            if (hh >= 0 && hh < Hh && ww >= 0 && ww < Ww) s += mask[hh * Ww + ww];
        }
    float avg = s * (1.f / 9.f);
    wm[pos] = mask[pos] / fmaxf(avg, 1e-8f);
}

// ---------------- zero a float4 buffer ----------------
__global__ __launch_bounds__(256) void k_zero(float4* __restrict__ p) {
    p[blockIdx.x * 256 + threadIdx.x] = make_float4(0.f, 0.f, 0.f, 0.f);
}

// ---------------- weight transforms: fp32 [oc][cin][3][3] -> bf16 [tap][oc][c64] ----
__global__ __launch_bounds__(256) void k_wx_res(const float* __restrict__ src,
                                                ushort_t* __restrict__ dst) {
    int idx = blockIdx.x * 256 + threadIdx.x;          // < 12*9*64*64 = 442368
    int j = idx / 36864; int rem = idx - j * 36864;
    int t = rem >> 12; int o = (rem >> 6) & 63; int c = rem & 63;
    dst[idx] = f2bf(src[j * 36864 + o * 576 + c * 9 + t]);
}
__global__ __launch_bounds__(256) void k_wx_out(const float* __restrict__ src,
                                                ushort_t* __restrict__ dst) {
    int idx = blockIdx.x * 256 + threadIdx.x;          // < 3*9*16*64 = 27648
    int i = idx / 9216; int rem = idx - i * 9216;
    int t = rem >> 10; int o = (rem >> 6) & 15; int c = rem & 63;
    dst[idx] = f2bf(src[i * 9216 + o * 576 + c * 9 + t]);
}
__global__ __launch_bounds__(256) void k_wx_trunk(const float* __restrict__ src,
                                                  ushort_t* __restrict__ dst) {
    int idx = blockIdx.x * 256 + threadIdx.x;          // < 4*9*48*64 = 110592
    int j = idx / 27648; int rem = idx - j * 27648;
    int t = rem / 3072; int rem2 = rem - t * 3072;
    int o = rem2 >> 6; int c = rem2 & 63;
    float v = (c < 48) ? src[j * (48 * 48 * 9) + o * 432 + c * 9 + t] : 0.f;
    dst[idx] = f2bf(v);
}
// MLP weights -> A-frag layout [out][k64] bf16, biases folded
__global__ __launch_bounds__(256) void k_wx_mlp(
    const float* __restrict__ w1, const float* __restrict__ b1,
    const float* __restrict__ w2, const float* __restrict__ b2,
    const float* __restrict__ w3, const float* __restrict__ b3,
    ushort_t* __restrict__ dst) {
    int idx = blockIdx.x * 256 + threadIdx.x;          // < 7168
    float v = 0.f;
    if (idx < 3072) {                                  // wA1 [48][64]
        int o = idx >> 6, c = idx & 63;
        v = (c < 49) ? w1[o * 49 + c] : (c == 49 ? b1[o] : 0.f);
    } else if (idx < 6144) {                           // wA2 [48][64]
        int o = (idx - 3072) >> 6, c = idx & 63;
        v = (c < 48) ? w2[o * 48 + c] : (c == 48 ? b2[o] : 0.f);
    } else {                                           // wA3 [16][64]
        int o = (idx - 6144) >> 6, c = idx & 63;
        if (o < 3) v = (c < 48) ? w3[o * 48 + c] : (c == 49 ? b3[o] : 0.f);
    }
    dst[idx] = f2bf(v);
}

// ------- xs: NCHW fp32 -> masked NHWC bf16, all pyramids (z = i*B + b) --------------
__global__ __launch_bounds__(256) void k_xm(const float* __restrict__ xs,
                                            const float* __restrict__ mask,
                                            ushort_t* __restrict__ X) {
    __shared__ float l[64 * 65];
    const int p0 = blockIdx.x * 64;
    const size_t zoff = (size_t)blockIdx.y * 64 * HW;
    const int tid = threadIdx.x;
    const int px = tid & 63;
    const float mv = mask[p0 + px];
    #pragma unroll
    for (int k = 0; k < 16; ++k) {
        int c = (tid >> 6) + 4 * k;
        l[c * 65 + px] = xs[zoff + (size_t)c * HW + p0 + px] * mv;
    }
    __syncthreads();
    #pragma unroll
    for (int k = 0; k < 2; ++k) {
        int idx = tid + k * 256;
        int p = idx >> 3, c8 = idx & 7;
        short8 v;
        #pragma unroll
        for (int i = 0; i < 8; ++i) v[i] = (short)f2bf(l[(c8 * 8 + i) * 65 + p]);
        *(short8*)&X[zoff + (size_t)(p0 + p) * 64 + c8 * 8] = v;
    }
}

// ---------------- MFMA implicit-GEMM 3x3 conv (NHWC bf16, ch stride 64) ------------
// TH=4 tile, wave wv owns row wv (2 col-frags). Act halo (208 rows x 128B, 26.6KB)
// staged ONCE (8-slot XOR swizzle, zero-page OOB). Weights: <=32-oc groups x 32-ch
// K-phases, DOUBLE-BUFFERED with counted vmcnt (5 DMA/wave/phase, uniform via pad
// slots) -> no vmem drain in steady state. Phase: issue-next, vmcnt(WV), barrier,
// MFMA, barrier. z = pyramid*2+batch (trunk z=batch, wstride=0). TOF: out->F chan
// (z>>1)*16. MODE 0: relu(conv*wm)  MODE 1: base+conv*wm  MODE 2: conv*wm
template <int OC, int MODE, bool TOF>
__global__ __launch_bounds__(256) void k_mconv(
    const ushort_t* __restrict__ in,
    const ushort_t* __restrict__ wgt, int wstride,
    const float* __restrict__ wm,
    const ushort_t* __restrict__ zp,      // >=256B of zeros, 16B aligned
    const ushort_t* __restrict__ base,
    ushort_t* __restrict__ out) {
    constexpr int NG = (OC + 31) / 32;
    constexpr int NPH = 2 * NG;
    constexpr int WSLOT = (OC >= 48) ? 20 : 12;   // 16-row slots per wgt buffer
    constexpr int WV = WSLOT / 4;                 // DMA per wave per phase (5 or 3)
    extern __shared__ __align__(1024) ushort_t smem[];
    ushort_t* alds  = smem;                       // 208*64 elems (26624B)
    ushort_t* wlds0 = smem + 208 * 64;
    ushort_t* wlds1 = wlds0 + WSLOT * 512;
    const int tid = threadIdx.x;
    const int wv = tid >> 6;
    const int ln = tid & 63;
    const int w0 = blockIdx.x * TW, h0 = blockIdx.y * TH;
    const int zz = blockIdx.z;
    const ushort_t* inb = in + (size_t)zz * HW * 64;
    const ushort_t* wB = wgt + (size_t)(zz >> 1) * wstride;
    const ushort_t* baseb = base ? base + (size_t)zz * HW * 64 : nullptr;
    ushort_t* outb = TOF ? out + (size_t)(zz & 1) * HW * 64 : out + (size_t)zz * HW * 64;
    const int ocb = TOF ? (zz >> 1) * 16 : 0;
    const int lo = ln & 15, slr = ln >> 4;

    auto wstage = [&](int p, ushort_t* wbuf) {
        const int gi = p >> 1, h = p & 1;
        const int ob = gi * 32;
        const int ocg = (OC - ob >= 32) ? 32 : 16;
        #pragma unroll
        for (int k = 0; k < WV; ++k) {
            int s = wv + 4 * k;                    // < WSLOT by construction
            int rl = s * 16 + (ln >> 2);
            int d = ln & 3;
            int j = d ^ ((rl ^ (rl >> 2)) & 3);
            int t, ol;
            if (ocg == 32) { t = rl >> 5; ol = rl & 31; }
            else           { t = rl >> 4; ol = rl & 15; }
            bool valid = rl < 9 * ocg;             // pad slots -> harmless re-read
            const ushort_t* src = valid
                ? wB + (size_t)(t * OC + ob + ol) * 64 + h * 32 + j * 8
                : wB + j * 8;
            gload_lds16(src, &wbuf[s * 512]);
        }
    };

    // ---- prologue: issue w-phase0 DMAs, then act DMAs (act completes under first
    //      vmcnt(WV) since it is older than phase1's loads) ----
    wstage(0, wlds0);
    #pragma unroll
    for (int k = 0; k < 7; ++k) {
        int s = wv + 4 * k;
        if (s < ASLOT) {
            int pp = s * 8 + (ln >> 3);            // 0..207
            int r = (pp * 241) >> 13;              // pp/34 for pp<352
            int col = pp - r * 34;
            int gh = h0 + r - 1, gw = w0 + col - 1;
            bool ok = (pp < HALOP4) & (gh >= 0) & (gh < Hh) & (gw >= 0) & (gw < Ww);
            int che = ((ln & 7) ^ (pp & 7)) << 3;
            const ushort_t* src = ok ? inb + (size_t)(gh * Ww + gw) * 64 + che : zp + che;
            gload_lds16(src, &alds[s * 512]);
        }
    }

    f32x4 acc[2][2];
    #pragma unroll
    for (int p = 0; p < NPH; ++p) {
        const int gi = p >> 1, h = p & 1;
        const int ob = gi * 32;
        const int ocg = (OC - ob >= 32) ? 32 : 16;
        const int nmg = ocg / 16;
        ushort_t* wcur = (p & 1) ? wlds1 : wlds0;
        if (p + 1 < NPH) {
            wstage(p + 1, (p & 1) ? wlds0 : wlds1);
            wait_vm<WV>();                         // prev phase (and act) complete
        } else {
            wait_vm<0>();
        }
        __syncthreads();

        if (h == 0) {
            #pragma unroll
            for (int mfl = 0; mfl < 2; ++mfl)
                #pragma unroll
                for (int nf = 0; nf < 2; ++nf) acc[mfl][nf] = (f32x4){0.f, 0.f, 0.f, 0.f};
        }

        #pragma unroll
        for (int dy = 0; dy < 3; ++dy)
            #pragma unroll
            for (int dx = 0; dx < 3; ++dx) {
                const int t = dy * 3 + dx;
                short8 afr[2];
                #pragma unroll
                for (int mfl = 0; mfl < 2; ++mfl) if (mfl < nmg) {
                    int rl = t * ocg + mfl * 16 + lo;
                    afr[mfl] = *(const short8*)
                        &wcur[rl * 32 + ((slr ^ ((rl ^ (rl >> 2)) & 3)) << 3)];
                }
                short8 bfr[2];
                #pragma unroll
                for (int nf = 0; nf < 2; ++nf) {
                    int pp2 = (wv + dy) * 34 + nf * 16 + lo + dx;
                    bfr[nf] = *(const short8*)
                        &alds[pp2 * 64 + (((h * 4 + slr) ^ (pp2 & 7)) << 3)];
                }
                #pragma unroll
                for (int mfl = 0; mfl < 2; ++mfl) if (mfl < nmg)
                    #pragma unroll
                    for (int nf = 0; nf < 2; ++nf)
                        acc[mfl][nf] = __builtin_amdgcn_mfma_f32_16x16x32_bf16(
                            afr[mfl], bfr[nf], acc[mfl][nf], 0, 0, 0);
            }

        if (h == 1) {
            // ---- group epilogue: C col=lane&15 (pixel), row=(lane>>4)*4+j ----
            #pragma unroll
            for (int nf = 0; nf < 2; ++nf) {
                int r = h0 + wv;
                int x = w0 + nf * 16 + lo;
                int pos = r * Ww + x;
                float wmv = wm[pos];
                #pragma unroll
                for (int mfl = 0; mfl < 2; ++mfl) if (mfl < nmg) {
                    int o0 = ocb + ob + mfl * 16 + slr * 4;
                    size_t oi = (size_t)pos * 64 + o0;
                    float v[4];
                    #pragma unroll
                    for (int q = 0; q < 4; ++q) v[q] = acc[mfl][nf][q] * wmv;
                    if (MODE == 0) {
                        #pragma unroll
                        for (int q = 0; q < 4; ++q) v[q] = fmaxf(v[q], 0.f);
                    } else if (MODE == 1) {
                        short4v bv = *(const short4v*)&baseb[oi];
                        #pragma unroll
                        for (int q = 0; q < 4; ++q) v[q] += bf2f((ushort_t)bv[q]);
                    }
                    short4v sv;
                    #pragma unroll
                    for (int q = 0; q < 4; ++q) sv[q] = (short)f2bf(v[q]);
                    *(short4v*)&outb[oi] = sv;
                }
            }
        }
        if (p + 1 < NPH) __syncthreads();          // WAR: protect buf (p+2)&1 issue
    }
}

// ---------------- gather + MLP via MFMA: 64 pts/block, 16 pts/wave --------------------
__global__ __launch_bounds__(256) void k_gather_mlp(
    const ushort_t* __restrict__ F, const ushort_t* __restrict__ G,
    const int* __restrict__ yi, const float* __restrict__ m,
    const ushort_t* __restrict__ wA1, const ushort_t* __restrict__ wA2,
    const ushort_t* __restrict__ wA3, float* __restrict__ pvd) {
    __shared__ __align__(16) ushort_t HA[4 * 16 * PADH];
    __shared__ __align__(16) ushort_t HB[4 * 16 * PADH];
    const int tid = threadIdx.x, wv = tid >> 6, ln = tid & 63;
    ushort_t* ha = HA + wv * 16 * PADH;
    ushort_t* hb = HB + wv * 16 * PADH;
    const int t0 = blockIdx.x * 64 + wv * 16;
    const int b = t0 >> 15;
    const int lo = ln & 15, g8 = (ln >> 4) * 8;

    #pragma unroll
    for (int rnd = 0; rnd < 2; ++rnd) {
        int j = rnd * 64 + ln;
        if (j < 96) {
            int pt = j / 6, sl = j - pt * 6;
            int n = (t0 + pt) & (Nn - 1);
            int pos = yi[n];
            size_t gi = ((size_t)(b * HW) + pos) * 64 + sl * 8;
            short8 fa = *(const short8*)&F[gi];
            short8 ga = *(const short8*)&G[gi];
            short8 sv;
            #pragma unroll
            for (int i = 0; i < 8; ++i)
                sv[i] = (short)f2bf(bf2f((ushort_t)fa[i]) + bf2f((ushort_t)ga[i]));
            *(short8*)&ha[pt * PADH + sl * 8] = sv;
        }
    }
    if (ln < 16) {
        int pt = ln;
        int n = (t0 + pt) & (Nn - 1);
        int pos = yi[n];
        float det = m[0] * (m[4] * m[8] - m[5] * m[7])
                  - m[1] * (m[3] * m[8] - m[5] * m[6])
                  + m[2] * (m[3] * m[7] - m[4] * m[6]);
        int yr = pos >> 8, xc = pos & 255;
        float wc = m[6] * (float)xc + m[7] * (float)yr + m[8];
        float cw = fmaxf(fabsf(wc), 1e-8f);
        float dsda = fabsf(det) / (cw * cw * cw);
        float ld = logf(dsda + 1e-8f);
        const ushort_t one = f2bf(1.0f);
        short8 z = {0, 0, 0, 0, 0, 0, 0, 0};
        short8 sa = z; sa[0] = (short)f2bf(ld); sa[1] = (short)one;
        short8 sb = z; sb[0] = (short)one;
        *(short8*)&ha[pt * PADH + 48] = sa;
        *(short8*)&ha[pt * PADH + 56] = z;
        *(short8*)&hb[pt * PADH + 48] = sb;
        *(short8*)&hb[pt * PADH + 56] = z;
    }
    asm volatile("s_waitcnt lgkmcnt(0)" ::: "memory");

    f32x4 a1[3] = {{0.f,0.f,0.f,0.f},{0.f,0.f,0.f,0.f},{0.f,0.f,0.f,0.f}};
    #pragma unroll
    for (int ks = 0; ks < 2; ++ks) {
        short8 bf = *(const short8*)&ha[lo * PADH + ks * 32 + g8];
        #pragma unroll
        for (int mf = 0; mf < 3; ++mf) {
            short8 af = *(const short8*)&wA1[(mf * 16 + lo) * 64 + ks * 32 + g8];
            a1[mf] = __builtin_amdgcn_mfma_f32_16x16x32_bf16(af, bf, a1[mf], 0, 0, 0);
        }
    }
    #pragma unroll
    for (int mf = 0; mf < 3; ++mf) {
        short4v sv;
        #pragma unroll
        for (int j = 0; j < 4; ++j) sv[j] = (short)f2bf(fmaxf(a1[mf][j], 0.f));
        *(short4v*)&hb[lo * PADH + mf * 16 + (ln >> 4) * 4] = sv;
    }
    asm volatile("s_waitcnt lgkmcnt(0)" ::: "memory");

    f32x4 a2[3] = {{0.f,0.f,0.f,0.f},{0.f,0.f,0.f,0.f},{0.f,0.f,0.f,0.f}};
    #pragma unroll
    for (int ks = 0; ks < 2; ++ks) {
        short8 bf = *(const short8*)&hb[lo * PADH + ks * 32 + g8];
        #pragma unroll
        for (int mf = 0; mf < 3; ++mf) {
            short8 af = *(const short8*)&wA2[(mf * 16 + lo) * 64 + ks * 32 + g8];
            a2[mf] = __builtin_amdgcn_mfma_f32_16x16x32_bf16(af, bf, a2[mf], 0, 0, 0);
        }
    }
    #pragma unroll
    for (int mf = 0; mf < 3; ++mf) {
        short4v sv;
        #pragma unroll
        for (int j = 0; j < 4; ++j) sv[j] = (short)f2bf(fmaxf(a2[mf][j], 0.f));
        *(short4v*)&ha[lo * PADH + mf * 16 + (ln >> 4) * 4] = sv;
    }
    asm volatile("s_waitcnt lgkmcnt(0)" ::: "memory");

    f32x4 a3 = {0.f, 0.f, 0.f, 0.f};
    #pragma unroll
    for (int ks = 0; ks < 2; ++ks) {
        short8 bf = *(const short8*)&ha[lo * PADH + ks * 32 + g8];
        short8 af = *(const short8*)&wA3[lo * 64 + ks * 32 + g8];
        a3 = __builtin_amdgcn_mfma_f32_16x16x32_bf16(af, bf, a3, 0, 0, 0);
    }
    if (ln < 16) {
        int n = (t0 + lo) & (Nn - 1);
        int pos = yi[n];
        #pragma unroll
        for (int j = 0; j < 3; ++j)
            pvd[(size_t)(b * Pp + j) * HW + pos] = a3[j];
    }
}

// ---------------- out[b,c,pos] = sum_p pvd[b,p,pos] * xs[p,b,c,pos] ----------------
__global__ __launch_bounds__(256) void k_blend(const float4* __restrict__ xs,
                                               const float4* __restrict__ pvd,
                                               float4* __restrict__ out) {
    int i = blockIdx.x * 256 + threadIdx.x;   // over B*C*HW/4
    int pos4 = i & (HW / 4 - 1);
    int bc = i >> 14;
    int b = bc >> 6;
    float4 acc = make_float4(0.f, 0.f, 0.f, 0.f);
    #pragma unroll
    for (int p = 0; p < Pp; ++p) {
        float4 pv = pvd[(b * Pp + p) * (HW / 4) + pos4];
        float4 x = xs[p * (Bb * Cc * HW / 4) + i];
        acc.x += pv.x * x.x;
        acc.y += pv.y * x.y;
        acc.z += pv.z * x.z;
        acc.w += pv.w * x.w;
    }
    out[i] = acc;
}

extern "C" void kernel_launch(void* const* d_in, const int* in_sizes, int n_in,
                              void* d_out, int out_size, void* d_ws, size_t ws_size,
                              hipStream_t stream) {
    const float* xs        = (const float*)d_in[0];
    const float* mask      = (const float*)d_in[1];
    const int*   yi        = (const int*)d_in[2];
    const float* m         = (const float*)d_in[3];
    const float* ss_res_w  = (const float*)d_in[4];
    const float* ss_out_w  = (const float*)d_in[5];
    const float* feat_res_w= (const float*)d_in[6];
    const float* w1 = (const float*)d_in[7];
    const float* b1 = (const float*)d_in[8];
    const float* w2 = (const float*)d_in[9];
    const float* b2 = (const float*)d_in[10];
    const float* w3 = (const float*)d_in[11];
    const float* b3 = (const float*)d_in[12];

    // ws: wm f32 | zpage | pvd f32 | wB | wA | X (P,B,HW,64) | U | V | F (B,HW,64) | G
    float* wm    = (float*)d_ws;
    float* zpage = wm + HW;
    float* pvd   = zpage + 64;
    ushort_t* wB = (ushort_t*)(pvd + (size_t)Bb * Pp * HW);
    constexpr size_t RES_T = 12 * 9 * 64 * 64;     // 442368
    constexpr size_t OUT_T = 3 * 9 * 16 * 64;      // 27648
    constexpr size_t TRK_T = 4 * 9 * 48 * 64;      // 110592
    constexpr size_t MLP_T = 7168;
    constexpr size_t ZT = (size_t)Pp * Bb * HW * 64;   // 25165824
    ushort_t* wA = wB + RES_T + OUT_T + TRK_T;
    ushort_t* X = wA + MLP_T;
    ushort_t* U = X + ZT;
    ushort_t* V = U + ZT;
    ushort_t* F = V + ZT;
    ushort_t* G = F + (size_t)Bb * HW * 64;
    const ushort_t* zp = (const ushort_t*)zpage;

    k_wm<<<HW / 256, 256, 0, stream>>>(mask, wm, zpage);
    k_wx_res  <<<RES_T / 256, 256, 0, stream>>>(ss_res_w, wB);
    k_wx_out  <<<OUT_T / 256, 256, 0, stream>>>(ss_out_w, wB + RES_T);
    k_wx_trunk<<<TRK_T / 256, 256, 0, stream>>>(feat_res_w, wB + RES_T + OUT_T);
    k_wx_mlp  <<<MLP_T / 256, 256, 0, stream>>>(w1, b1, w2, b2, w3, b3, wA);

    const dim3 gridP(Ww / TW, Hh / TH, Pp * Bb);   // (8, 64, 6)
    const dim3 gridT(Ww / TW, Hh / TH, Bb);        // (8, 64, 2)
    const int RS = 4 * 9 * 64 * 64;                // per-pyramid res weight stride
    const int OS = 9 * 16 * 64;                    // per-pyramid out weight stride
    constexpr size_t SH64 = 26624 + 2 * 20 * 1024; // 67584 -> 2 blocks/CU
    constexpr size_t SH48 = SH64;
    constexpr size_t SH16 = 26624 + 2 * 12 * 1024; // 51200 -> 3 blocks/CU

    k_xm<<<dim3(HW / 64, Pp * Bb), 256, 0, stream>>>(xs, mask, X);
    k_mconv<64, 0, false><<<gridP, 256, SH64, stream>>>(X, wB,             RS, wm, zp, nullptr, U);
    k_mconv<64, 1, false><<<gridP, 256, SH64, stream>>>(U, wB + 1 * 36864, RS, wm, zp, X,       V);
    k_mconv<64, 0, false><<<gridP, 256, SH64, stream>>>(V, wB + 2 * 36864, RS, wm, zp, nullptr, U);
    k_mconv<64, 1, false><<<gridP, 256, SH64, stream>>>(U, wB + 3 * 36864, RS, wm, zp, V,       V);
    k_mconv<16, 2, true ><<<gridP, 256, SH16, stream>>>(V, wB + RES_T,     OS, wm, zp, nullptr, F);

    const ushort_t* tw = wB + RES_T + OUT_T;
    k_mconv<48, 0, false><<<gridT, 256, SH48, stream>>>(F, tw,             0, wm, zp, nullptr, U);
    k_mconv<48, 1, false><<<gridT, 256, SH48, stream>>>(U, tw + 1 * 27648, 0, wm, zp, F,       G);
    k_mconv<48, 0, false><<<gridT, 256, SH48, stream>>>(G, tw + 2 * 27648, 0, wm, zp, nullptr, U);
    k_mconv<48, 1, false><<<gridT, 256, SH48, stream>>>(U, tw + 3 * 27648, 0, wm, zp, G,       G);

    k_zero<<<(Bb * Pp * HW / 4) / 256, 256, 0, stream>>>((float4*)pvd);
    k_gather_mlp<<<Bb * Nn / 64, 256, 0, stream>>>(F, G, yi, m,
        wA, wA + 3072, wA + 6144, pvd);
    k_blend<<<(Bb * Cc * HW / 4) / 256, 256, 0, stream>>>((const float4*)xs, (const float4*)pvd,
                                                          (float4*)d_out);
}

// Round 13
// 325.261 us; speedup vs baseline: 1.1968x; 1.0457x over previous
//
#include <hip/hip_runtime.h>
#include <hip/hip_bf16.h>

typedef unsigned short ushort_t;
typedef __attribute__((ext_vector_type(8))) short short8;
typedef __attribute__((ext_vector_type(4))) short short4v;
typedef __attribute__((ext_vector_type(4))) float f32x4;

// Problem constants
constexpr int Hh = 256, Ww = 256, HW = Hh * Ww;
constexpr int Bb = 2, Cc = 64, Pp = 3, NOo = 16, FEXc = 48, Nn = 32768;
constexpr int TW = 32, TH = 4;       // conv tile per block
constexpr int HALOP4 = 6 * 34;       // 204 halo pixels
constexpr int ASLOT = 26;            // act DMA slots (8 rows each) -> 208 rows
constexpr int PADH = 72;             // gather-MLP LDS point stride (bf16)

__device__ inline ushort_t f2bf(float v) {
    __hip_bfloat16 h = __float2bfloat16(v);
    return *(ushort_t*)&h;
}
__device__ inline float bf2f(ushort_t u) {
    __hip_bfloat16 h = *(__hip_bfloat16*)&u;
    return __bfloat162float(h);
}
// async 16B global->LDS DMA: dest = lds base (wave-uniform) + lane*16
__device__ inline void gload_lds16(const ushort_t* g, ushort_t* l) {
    __builtin_amdgcn_global_load_lds(
        (const __attribute__((address_space(1))) unsigned int*)g,
        (__attribute__((address_space(3))) unsigned int*)l, 16, 0, 0);
}
template <int N>
__device__ __forceinline__ void wait_vm() {
    if constexpr (N == 0) asm volatile("s_waitcnt vmcnt(0)" ::: "memory");
    else if constexpr (N == 3) asm volatile("s_waitcnt vmcnt(3)" ::: "memory");
    else if constexpr (N == 5) asm volatile("s_waitcnt vmcnt(5)" ::: "memory");
}
// raw barrier WITHOUT the __syncthreads vmcnt(0) drain; compiler fence prevents
// LDS-value CSE across it (phases p and p+2 read the same wlds addresses)
__device__ __forceinline__ void raw_barrier() {
    asm volatile("" ::: "memory");
    __builtin_amdgcn_s_barrier();
    asm volatile("" ::: "memory");
}

// -------- mask weight: wm = mask / max(avg3x3(mask), 1e-8); also zero the zpage ------
__global__ __launch_bounds__(256) void k_wm(const float* __restrict__ mask,
                                            float* __restrict__ wm,
                                            float* __restrict__ zpage) {
    int pos = blockIdx.x * 256 + threadIdx.x;
    if (blockIdx.x == 0 && threadIdx.x < 64) zpage[threadIdx.x] = 0.f;  // 256B zeros
    int h = pos >> 8, w = pos & 255;
    float s = 0.f;
    #pragma unroll
    for (int dy = -1; dy <= 1; ++dy)
        #pragma unroll
        for (int dx = -1; dx <= 1; ++dx) {
            int hh = h + dy, ww = w + dx;
            if (hh >= 0 && hh < Hh && ww >= 0 && ww < Ww) s += mask[hh * Ww + ww];
        }
    float avg = s * (1.f / 9.f);
    wm[pos] = mask[pos] / fmaxf(avg, 1e-8f);
}

// ---------------- zero a float4 buffer ----------------
__global__ __launch_bounds__(256) void k_zero(float4* __restrict__ p) {
    p[blockIdx.x * 256 + threadIdx.x] = make_float4(0.f, 0.f, 0.f, 0.f);
}

// ---------------- weight transforms: fp32 [oc][cin][3][3] -> bf16 [tap][oc][c64] ----
__global__ __launch_bounds__(256) void k_wx_res(const float* __restrict__ src,
                                                ushort_t* __restrict__ dst) {
    int idx = blockIdx.x * 256 + threadIdx.x;          // < 12*9*64*64 = 442368
    int j = idx / 36864; int rem = idx - j * 36864;
    int t = rem >> 12; int o = (rem >> 6) & 63; int c = rem & 63;
    dst[idx] = f2bf(src[j * 36864 + o * 576 + c * 9 + t]);
}
__global__ __launch_bounds__(256) void k_wx_out(const float* __restrict__ src,
                                                ushort_t* __restrict__ dst) {
    int idx = blockIdx.x * 256 + threadIdx.x;          // < 3*9*16*64 = 27648
    int i = idx / 9216; int rem = idx - i * 9216;
    int t = rem >> 10; int o = (rem >> 6) & 15; int c = rem & 63;
    dst[idx] = f2bf(src[i * 9216 + o * 576 + c * 9 + t]);
}
__global__ __launch_bounds__(256) void k_wx_trunk(const float* __restrict__ src,
                                                  ushort_t* __restrict__ dst) {
    int idx = blockIdx.x * 256 + threadIdx.x;          // < 4*9*48*64 = 110592
    int j = idx / 27648; int rem = idx - j * 27648;
    int t = rem / 3072; int rem2 = rem - t * 3072;
    int o = rem2 >> 6; int c = rem2 & 63;
    float v = (c < 48) ? src[j * (48 * 48 * 9) + o * 432 + c * 9 + t] : 0.f;
    dst[idx] = f2bf(v);
}
// MLP weights -> A-frag layout [out][k64] bf16, biases folded
__global__ __launch_bounds__(256) void k_wx_mlp(
    const float* __restrict__ w1, const float* __restrict__ b1,
    const float* __restrict__ w2, const float* __restrict__ b2,
    const float* __restrict__ w3, const float* __restrict__ b3,
    ushort_t* __restrict__ dst) {
    int idx = blockIdx.x * 256 + threadIdx.x;          // < 7168
    float v = 0.f;
    if (idx < 3072) {                                  // wA1 [48][64]
        int o = idx >> 6, c = idx & 63;
        v = (c < 49) ? w1[o * 49 + c] : (c == 49 ? b1[o] : 0.f);
    } else if (idx < 6144) {                           // wA2 [48][64]
        int o = (idx - 3072) >> 6, c = idx & 63;
        v = (c < 48) ? w2[o * 48 + c] : (c == 48 ? b2[o] : 0.f);
    } else {                                           // wA3 [16][64]
        int o = (idx - 6144) >> 6, c = idx & 63;
        if (o < 3) v = (c < 48) ? w3[o * 48 + c] : (c == 49 ? b3[o] : 0.f);
    }
    dst[idx] = f2bf(v);
}

// ------- xs: NCHW fp32 -> masked NHWC bf16, all pyramids (z = i*B + b) --------------
__global__ __launch_bounds__(256) void k_xm(const float* __restrict__ xs,
                                            const float* __restrict__ mask,
                                            ushort_t* __restrict__ X) {
    __shared__ float l[64 * 65];
    const int p0 = blockIdx.x * 64;
    const size_t zoff = (size_t)blockIdx.y * 64 * HW;
    const int tid = threadIdx.x;
    const int px = tid & 63;
    const float mv = mask[p0 + px];
    #pragma unroll
    for (int k = 0; k < 16; ++k) {
        int c = (tid >> 6) + 4 * k;
        l[c * 65 + px] = xs[zoff + (size_t)c * HW + p0 + px] * mv;
    }
    __syncthreads();
    #pragma unroll
    for (int k = 0; k < 2; ++k) {
        int idx = tid + k * 256;
        int p = idx >> 3, c8 = idx & 7;
        short8 v;
        #pragma unroll
        for (int i = 0; i < 8; ++i) v[i] = (short)f2bf(l[(c8 * 8 + i) * 65 + p]);
        *(short8*)&X[zoff + (size_t)(p0 + p) * 64 + c8 * 8] = v;
    }
}

// ---------------- MFMA implicit-GEMM 3x3 conv (NHWC bf16, ch stride 64) ------------
// TH=4 tile, wave wv owns row wv (2 col-frags). Act halo (208 rows x 128B, 26.6KB)
// staged ONCE (8-slot XOR swizzle, zero-page OOB). Weights: <=32-oc groups x 32-ch
// K-phases, DOUBLE-BUFFERED with counted vmcnt + RAW s_barrier (no __syncthreads
// vmcnt(0) drain) -> next-phase weight DMAs stay in flight across barriers.
// z = pyramid*2+batch (trunk z=batch, wstride=0). TOF: out->F chan (z>>1)*16.
// MODE 0: relu(conv*wm)  MODE 1: base+conv*wm  MODE 2: conv*wm
template <int OC, int MODE, bool TOF>
__global__ __launch_bounds__(256) void k_mconv(
    const ushort_t* __restrict__ in,
    const ushort_t* __restrict__ wgt, int wstride,
    const float* __restrict__ wm,
    const ushort_t* __restrict__ zp,      // >=256B of zeros, 16B aligned
    const ushort_t* __restrict__ base,
    ushort_t* __restrict__ out) {
    constexpr int NG = (OC + 31) / 32;
    constexpr int NPH = 2 * NG;
    constexpr int WSLOT = (OC >= 48) ? 20 : 12;   // 16-row slots per wgt buffer
    constexpr int WV = WSLOT / 4;                 // DMA per wave per phase (5 or 3)
    extern __shared__ __align__(1024) ushort_t smem[];
    ushort_t* alds  = smem;                       // 208*64 elems (26624B)
    ushort_t* wlds0 = smem + 208 * 64;
    ushort_t* wlds1 = wlds0 + WSLOT * 512;
    const int tid = threadIdx.x;
    const int wv = tid >> 6;
    const int ln = tid & 63;
    const int w0 = blockIdx.x * TW, h0 = blockIdx.y * TH;
    const int zz = blockIdx.z;
    const ushort_t* inb = in + (size_t)zz * HW * 64;
    const ushort_t* wB = wgt + (size_t)(zz >> 1) * wstride;
    const ushort_t* baseb = base ? base + (size_t)zz * HW * 64 : nullptr;
    ushort_t* outb = TOF ? out + (size_t)(zz & 1) * HW * 64 : out + (size_t)zz * HW * 64;
    const int ocb = TOF ? (zz >> 1) * 16 : 0;
    const int lo = ln & 15, slr = ln >> 4;

    auto wstage = [&](int p, ushort_t* wbuf) {
        const int gi = p >> 1, h = p & 1;
        const int ob = gi * 32;
        const int ocg = (OC - ob >= 32) ? 32 : 16;
        #pragma unroll
        for (int k = 0; k < WV; ++k) {
            int s = wv + 4 * k;                    // < WSLOT by construction
            int rl = s * 16 + (ln >> 2);
            int d = ln & 3;
            int j = d ^ ((rl ^ (rl >> 2)) & 3);
            int t, ol;
            if (ocg == 32) { t = rl >> 5; ol = rl & 31; }
            else           { t = rl >> 4; ol = rl & 15; }
            bool valid = rl < 9 * ocg;             // pad slots -> harmless re-read
            const ushort_t* src = valid
                ? wB + (size_t)(t * OC + ob + ol) * 64 + h * 32 + j * 8
                : wB + j * 8;
            gload_lds16(src, &wbuf[s * 512]);
        }
    };

    // ---- prologue: issue w-phase0 DMAs, then act DMAs (both retire under the
    //      first counted vmcnt since they are older than phase1's loads) ----
    wstage(0, wlds0);
    #pragma unroll
    for (int k = 0; k < 7; ++k) {
        int s = wv + 4 * k;
        if (s < ASLOT) {
            int pp = s * 8 + (ln >> 3);            // 0..207
            int r = (pp * 241) >> 13;              // pp/34 for pp<352
            int col = pp - r * 34;
            int gh = h0 + r - 1, gw = w0 + col - 1;
            bool ok = (pp < HALOP4) & (gh >= 0) & (gh < Hh) & (gw >= 0) & (gw < Ww);
            int che = ((ln & 7) ^ (pp & 7)) << 3;
            const ushort_t* src = ok ? inb + (size_t)(gh * Ww + gw) * 64 + che : zp + che;
            gload_lds16(src, &alds[s * 512]);
        }
    }

    f32x4 acc[2][2];
    #pragma unroll
    for (int p = 0; p < NPH; ++p) {
        const int gi = p >> 1, h = p & 1;
        const int ob = gi * 32;
        const int ocg = (OC - ob >= 32) ? 32 : 16;
        const int nmg = ocg / 16;
        ushort_t* wcur = (p & 1) ? wlds1 : wlds0;
        if (p + 1 < NPH) {
            wstage(p + 1, (p & 1) ? wlds0 : wlds1);
            wait_vm<WV>();                         // prev phase (and act) complete
        } else {
            wait_vm<0>();
        }
        raw_barrier();                             // no vmcnt(0) drain here

        if (h == 0) {
            #pragma unroll
            for (int mfl = 0; mfl < 2; ++mfl)
                #pragma unroll
                for (int nf = 0; nf < 2; ++nf) acc[mfl][nf] = (f32x4){0.f, 0.f, 0.f, 0.f};
        }

        #pragma unroll
        for (int dy = 0; dy < 3; ++dy)
            #pragma unroll
            for (int dx = 0; dx < 3; ++dx) {
                const int t = dy * 3 + dx;
                short8 afr[2];
                #pragma unroll
                for (int mfl = 0; mfl < 2; ++mfl) if (mfl < nmg) {
                    int rl = t * ocg + mfl * 16 + lo;
                    afr[mfl] = *(const short8*)
                        &wcur[rl * 32 + ((slr ^ ((rl ^ (rl >> 2)) & 3)) << 3)];
                }
                short8 bfr[2];
                #pragma unroll
                for (int nf = 0; nf < 2; ++nf) {
                    int pp2 = (wv + dy) * 34 + nf * 16 + lo + dx;
                    bfr[nf] = *(const short8*)
                        &alds[pp2 * 64 + (((h * 4 + slr) ^ (pp2 & 7)) << 3)];
                }
                #pragma unroll
                for (int mfl = 0; mfl < 2; ++mfl) if (mfl < nmg)
                    #pragma unroll
                    for (int nf = 0; nf < 2; ++nf)
                        acc[mfl][nf] = __builtin_amdgcn_mfma_f32_16x16x32_bf16(
                            afr[mfl], bfr[nf], acc[mfl][nf], 0, 0, 0);
            }

        if (h == 1) {
            // ---- group epilogue: C col=lane&15 (pixel), row=(lane>>4)*4+j ----
            #pragma unroll
            for (int nf = 0; nf < 2; ++nf) {
                int r = h0 + wv;
                int x = w0 + nf * 16 + lo;
                int pos = r * Ww + x;
                float wmv = wm[pos];
                #pragma unroll
                for (int mfl = 0; mfl < 2; ++mfl) if (mfl < nmg) {
                    int o0 = ocb + ob + mfl * 16 + slr * 4;
                    size_t oi = (size_t)pos * 64 + o0;
                    float v[4];
                    #pragma unroll
                    for (int q = 0; q < 4; ++q) v[q] = acc[mfl][nf][q] * wmv;
                    if (MODE == 0) {
                        #pragma unroll
                        for (int q = 0; q < 4; ++q) v[q] = fmaxf(v[q], 0.f);
                    } else if (MODE == 1) {
                        short4v bv = *(const short4v*)&baseb[oi];
                        #pragma unroll
                        for (int q = 0; q < 4; ++q) v[q] += bf2f((ushort_t)bv[q]);
                    }
                    short4v sv;
                    #pragma unroll
                    for (int q = 0; q < 4; ++q) sv[q] = (short)f2bf(v[q]);
                    *(short4v*)&outb[oi] = sv;
                }
            }
        }
        if (p + 1 < NPH) raw_barrier();            // WAR: protect buf (p+2)&1 issue
    }
}

// ---------------- gather + MLP via MFMA: 64 pts/block, 16 pts/wave --------------------
__global__ __launch_bounds__(256) void k_gather_mlp(
    const ushort_t* __restrict__ F, const ushort_t* __restrict__ G,
    const int* __restrict__ yi, const float* __restrict__ m,
    const ushort_t* __restrict__ wA1, const ushort_t* __restrict__ wA2,
    const ushort_t* __restrict__ wA3, float* __restrict__ pvd) {
    __shared__ __align__(16) ushort_t HA[4 * 16 * PADH];
    __shared__ __align__(16) ushort_t HB[4 * 16 * PADH];
    const int tid = threadIdx.x, wv = tid >> 6, ln = tid & 63;
    ushort_t* ha = HA + wv * 16 * PADH;
    ushort_t* hb = HB + wv * 16 * PADH;
    const int t0 = blockIdx.x * 64 + wv * 16;
    const int b = t0 >> 15;
    const int lo = ln & 15, g8 = (ln >> 4) * 8;

    #pragma unroll
    for (int rnd = 0; rnd < 2; ++rnd) {
        int j = rnd * 64 + ln;
        if (j < 96) {
            int pt = j / 6, sl = j - pt * 6;
            int n = (t0 + pt) & (Nn - 1);
            int pos = yi[n];
            size_t gi = ((size_t)(b * HW) + pos) * 64 + sl * 8;
            short8 fa = *(const short8*)&F[gi];
            short8 ga = *(const short8*)&G[gi];
            short8 sv;
            #pragma unroll
            for (int i = 0; i < 8; ++i)
                sv[i] = (short)f2bf(bf2f((ushort_t)fa[i]) + bf2f((ushort_t)ga[i]));
            *(short8*)&ha[pt * PADH + sl * 8] = sv;
        }
    }
    if (ln < 16) {
        int pt = ln;
        int n = (t0 + pt) & (Nn - 1);
        int pos = yi[n];
        float det = m[0] * (m[4] * m[8] - m[5] * m[7])
                  - m[1] * (m[3] * m[8] - m[5] * m[6])
                  + m[2] * (m[3] * m[7] - m[4] * m[6]);
        int yr = pos >> 8, xc = pos & 255;
        float wc = m[6] * (float)xc + m[7] * (float)yr + m[8];
        float cw = fmaxf(fabsf(wc), 1e-8f);
        float dsda = fabsf(det) / (cw * cw * cw);
        float ld = logf(dsda + 1e-8f);
        const ushort_t one = f2bf(1.0f);
        short8 z = {0, 0, 0, 0, 0, 0, 0, 0};
        short8 sa = z; sa[0] = (short)f2bf(ld); sa[1] = (short)one;
        short8 sb = z; sb[0] = (short)one;
        *(short8*)&ha[pt * PADH + 48] = sa;
        *(short8*)&ha[pt * PADH + 56] = z;
        *(short8*)&hb[pt * PADH + 48] = sb;
        *(short8*)&hb[pt * PADH + 56] = z;
    }
    asm volatile("s_waitcnt lgkmcnt(0)" ::: "memory");

    f32x4 a1[3] = {{0.f,0.f,0.f,0.f},{0.f,0.f,0.f,0.f},{0.f,0.f,0.f,0.f}};
    #pragma unroll
    for (int ks = 0; ks < 2; ++ks) {
        short8 bf = *(const short8*)&ha[lo * PADH + ks * 32 + g8];
        #pragma unroll
        for (int mf = 0; mf < 3; ++mf) {
            short8 af = *(const short8*)&wA1[(mf * 16 + lo) * 64 + ks * 32 + g8];
            a1[mf] = __builtin_amdgcn_mfma_f32_16x16x32_bf16(af, bf, a1[mf], 0, 0, 0);
        }
    }
    #pragma unroll
    for (int mf = 0; mf < 3; ++mf) {
        short4v sv;
        #pragma unroll
        for (int j = 0; j < 4; ++j) sv[j] = (short)f2bf(fmaxf(a1[mf][j], 0.f));
        *(short4v*)&hb[lo * PADH + mf * 16 + (ln >> 4) * 4] = sv;
    }
    asm volatile("s_waitcnt lgkmcnt(0)" ::: "memory");

    f32x4 a2[3] = {{0.f,0.f,0.f,0.f},{0.f,0.f,0.f,0.f},{0.f,0.f,0.f,0.f}};
    #pragma unroll
    for (int ks = 0; ks < 2; ++ks) {
        short8 bf = *(const short8*)&hb[lo * PADH + ks * 32 + g8];
        #pragma unroll
        for (int mf = 0; mf < 3; ++mf) {
            short8 af = *(const short8*)&wA2[(mf * 16 + lo) * 64 + ks * 32 + g8];
            a2[mf] = __builtin_amdgcn_mfma_f32_16x16x32_bf16(af, bf, a2[mf], 0, 0, 0);
        }
    }
    #pragma unroll
    for (int mf = 0; mf < 3; ++mf) {
        short4v sv;
        #pragma unroll
        for (int j = 0; j < 4; ++j) sv[j] = (short)f2bf(fmaxf(a2[mf][j], 0.f));
        *(short4v*)&ha[lo * PADH + mf * 16 + (ln >> 4) * 4] = sv;
    }
    asm volatile("s_waitcnt lgkmcnt(0)" ::: "memory");

    f32x4 a3 = {0.f, 0.f, 0.f, 0.f};
    #pragma unroll
    for (int ks = 0; ks < 2; ++ks) {
        short8 bf = *(const short8*)&ha[lo * PADH + ks * 32 + g8];
        short8 af = *(const short8*)&wA3[lo * 64 + ks * 32 + g8];
        a3 = __builtin_amdgcn_mfma_f32_16x16x32_bf16(af, bf, a3, 0, 0, 0);
    }
    if (ln < 16) {
        int n = (t0 + lo) & (Nn - 1);
        int pos = yi[n];
        #pragma unroll
        for (int j = 0; j < 3; ++j)
            pvd[(size_t)(b * Pp + j) * HW + pos] = a3[j];
    }
}

// ---------------- out[b,c,pos] = sum_p pvd[b,p,pos] * xs[p,b,c,pos] ----------------
__global__ __launch_bounds__(256) void k_blend(const float4* __restrict__ xs,
                                               const float4* __restrict__ pvd,
                                               float4* __restrict__ out) {
    int i = blockIdx.x * 256 + threadIdx.x;   // over B*C*HW/4
    int pos4 = i & (HW / 4 - 1);
    int bc = i >> 14;
    int b = bc >> 6;
    float4 acc = make_float4(0.f, 0.f, 0.f, 0.f);
    #pragma unroll
    for (int p = 0; p < Pp; ++p) {
        float4 pv = pvd[(b * Pp + p) * (HW / 4) + pos4];
        float4 x = xs[p * (Bb * Cc * HW / 4) + i];
        acc.x += pv.x * x.x;
        acc.y += pv.y * x.y;
        acc.z += pv.z * x.z;
        acc.w += pv.w * x.w;
    }
    out[i] = acc;
}

extern "C" void kernel_launch(void* const* d_in, const int* in_sizes, int n_in,
                              void* d_out, int out_size, void* d_ws, size_t ws_size,
                              hipStream_t stream) {
    const float* xs        = (const float*)d_in[0];
    const float* mask      = (const float*)d_in[1];
    const int*   yi        = (const int*)d_in[2];
    const float* m         = (const float*)d_in[3];
    const float* ss_res_w  = (const float*)d_in[4];
    const float* ss_out_w  = (const float*)d_in[5];
    const float* feat_res_w= (const float*)d_in[6];
    const float* w1 = (const float*)d_in[7];
    const float* b1 = (const float*)d_in[8];
    const float* w2 = (const float*)d_in[9];
    const float* b2 = (const float*)d_in[10];
    const float* w3 = (const float*)d_in[11];
    const float* b3 = (const float*)d_in[12];

    // ws: wm f32 | zpage | pvd f32 | wB | wA | X (P,B,HW,64) | U | V | F (B,HW,64) | G
    float* wm    = (float*)d_ws;
    float* zpage = wm + HW;
    float* pvd   = zpage + 64;
    ushort_t* wB = (ushort_t*)(pvd + (size_t)Bb * Pp * HW);
    constexpr size_t RES_T = 12 * 9 * 64 * 64;     // 442368
    constexpr size_t OUT_T = 3 * 9 * 16 * 64;      // 27648
    constexpr size_t TRK_T = 4 * 9 * 48 * 64;      // 110592
    constexpr size_t MLP_T = 7168;
    constexpr size_t ZT = (size_t)Pp * Bb * HW * 64;   // 25165824
    ushort_t* wA = wB + RES_T + OUT_T + TRK_T;
    ushort_t* X = wA + MLP_T;
    ushort_t* U = X + ZT;
    ushort_t* V = U + ZT;
    ushort_t* F = V + ZT;
    ushort_t* G = F + (size_t)Bb * HW * 64;
    const ushort_t* zp = (const ushort_t*)zpage;

    k_wm<<<HW / 256, 256, 0, stream>>>(mask, wm, zpage);
    k_wx_res  <<<RES_T / 256, 256, 0, stream>>>(ss_res_w, wB);
    k_wx_out  <<<OUT_T / 256, 256, 0, stream>>>(ss_out_w, wB + RES_T);
    k_wx_trunk<<<TRK_T / 256, 256, 0, stream>>>(feat_res_w, wB + RES_T + OUT_T);
    k_wx_mlp  <<<MLP_T / 256, 256, 0, stream>>>(w1, b1, w2, b2, w3, b3, wA);

    const dim3 gridP(Ww / TW, Hh / TH, Pp * Bb);   // (8, 64, 6)
    const dim3 gridT(Ww / TW, Hh / TH, Bb);        // (8, 64, 2)
    const int RS = 4 * 9 * 64 * 64;                // per-pyramid res weight stride
    const int OS = 9 * 16 * 64;                    // per-pyramid out weight stride
    constexpr size_t SH64 = 26624 + 2 * 20 * 1024; // 67584 -> 2 blocks/CU
    constexpr size_t SH48 = SH64;
    constexpr size_t SH16 = 26624 + 2 * 12 * 1024; // 51200 -> 3 blocks/CU

    k_xm<<<dim3(HW / 64, Pp * Bb), 256, 0, stream>>>(xs, mask, X);
    k_mconv<64, 0, false><<<gridP, 256, SH64, stream>>>(X, wB,             RS, wm, zp, nullptr, U);
    k_mconv<64, 1, false><<<gridP, 256, SH64, stream>>>(U, wB + 1 * 36864, RS, wm, zp, X,       V);
    k_mconv<64, 0, false><<<gridP, 256, SH64, stream>>>(V, wB + 2 * 36864, RS, wm, zp, nullptr, U);
    k_mconv<64, 1, false><<<gridP, 256, SH64, stream>>>(U, wB + 3 * 36864, RS, wm, zp, V,       V);
    k_mconv<16, 2, true ><<<gridP, 256, SH16, stream>>>(V, wB + RES_T,     OS, wm, zp, nullptr, F);

    const ushort_t* tw = wB + RES_T + OUT_T;
    k_mconv<48, 0, false><<<gridT, 256, SH48, stream>>>(F, tw,             0, wm, zp, nullptr, U);
    k_mconv<48, 1, false><<<gridT, 256, SH48, stream>>>(U, tw + 1 * 27648, 0, wm, zp, F,       G);
    k_mconv<48, 0, false><<<gridT, 256, SH48, stream>>>(G, tw + 2 * 27648, 0, wm, zp, nullptr, U);
    k_mconv<48, 1, false><<<gridT, 256, SH48, stream>>>(U, tw + 3 * 27648, 0, wm, zp, G,       G);

    k_zero<<<(Bb * Pp * HW / 4) / 256, 256, 0, stream>>>((float4*)pvd);
    k_gather_mlp<<<Bb * Nn / 64, 256, 0, stream>>>(F, G, yi, m,
        wA, wA + 3072, wA + 6144, pvd);
    k_blend<<<(Bb * Cc * HW / 4) / 256, 256, 0, stream>>>((const float4*)xs, (const float4*)pvd,
                                                          (float4*)d_out);
}